// Round 1
// baseline (166.368 us; speedup 1.0000x reference)
//
#include <hip/hip_runtime.h>

#define TT   1024
#define HID  16
#define KK   5
#define NF   32
#define SEG  256
#define DD   4

// One block per (b, f). 256 threads = 4 waves; wave w owns pool segment w.
__global__ __launch_bounds__(256, 2) void branch_kernel(
    const float* __restrict__ x,   // (B, T, F)
    const float* __restrict__ w1,  // (F, HID, 1, K)
    const float* __restrict__ b1,  // (F, HID)
    const float* __restrict__ w2,  // (F, HID, HID, K)
    const float* __restrict__ b2,  // (F, HID)
    const float* __restrict__ pw,  // (F, D, HID*D)
    const float* __restrict__ pb,  // (F, D)
    float* __restrict__ out)       // (B, F*D)
{
    const int f   = blockIdx.x;
    const int b   = blockIdx.y;
    const int tid = threadIdx.x;

    __shared__ float xrow[TT + 4];
    __shared__ float h1[HID][TT + 4];          // [cin][t+2], halo zeros
    __shared__ float w2l[HID * KK * HID];      // [cin][k][c]
    __shared__ float pool[HID * DD];

    // ---- stage x row (strided gather; L2/L3 absorbs re-reads across f) ----
    const float* xb = x + (size_t)b * TT * NF + f;
    #pragma unroll
    for (int p = 0; p < 4; ++p) {
        int t = tid + 256 * p;
        xrow[t + 2] = xb[(size_t)t * NF];
    }
    if (tid < 2) { xrow[tid] = 0.f; xrow[TT + 2 + tid] = 0.f; }

    // ---- stage w2 transposed to [cin][k][c] ----
    const float* w2f = w2 + (size_t)f * (HID * HID * KK);
    #pragma unroll
    for (int p = 0; p < 5; ++p) {
        int i = tid + 256 * p;             // i = c*80 + cin*5 + k
        float v = w2f[i];
        int c   = i / (HID * KK);
        int r   = i - c * (HID * KK);
        int cin = r / KK;
        int k   = r - cin * KK;
        w2l[(cin * KK + k) * HID + c] = v;
    }

    // ---- zero h1 halos ----
    if (tid < HID) {
        h1[tid][0] = 0.f; h1[tid][1] = 0.f;
        h1[tid][TT + 2] = 0.f; h1[tid][TT + 3] = 0.f;
    }
    __syncthreads();

    // ---- conv1: x -> h1 (relu) ----
    const float* w1f = w1 + f * (HID * KK);
    const float* b1f = b1 + f * HID;
    #pragma unroll
    for (int p = 0; p < 4; ++p) {
        int t = tid + 256 * p;
        float xv[KK];
        #pragma unroll
        for (int k = 0; k < KK; ++k) xv[k] = xrow[t + k];
        #pragma unroll
        for (int c = 0; c < HID; ++c) {
            float a = b1f[c];
            #pragma unroll
            for (int k = 0; k < KK; ++k) a = fmaf(w1f[c * KK + k], xv[k], a);
            h1[c][t + 2] = fmaxf(a, 0.f);
        }
    }
    __syncthreads();

    // ---- conv2 + relu + pool ----
    // wave s handles segment s; lane l handles columns tbase + 64*q (q<4)
    const float* b2f = b2 + f * HID;
    const int s = tid >> 6;
    const int l = tid & 63;
    const int tbase = s * SEG + l;

    float acc[4][HID];
    #pragma unroll
    for (int q = 0; q < 4; ++q)
        #pragma unroll
        for (int c = 0; c < HID; ++c) acc[q][c] = b2f[c];

    #pragma unroll 4
    for (int cin = 0; cin < HID; ++cin) {
        float hw[4][KK];
        #pragma unroll
        for (int q = 0; q < 4; ++q) {
            int jj = tbase + 64 * q;     // output time t = jj; reads h1[t + k]
            #pragma unroll
            for (int k = 0; k < KK; ++k) hw[q][k] = h1[cin][jj + k];
        }
        #pragma unroll
        for (int k = 0; k < KK; ++k) {
            float wv[HID];
            #pragma unroll
            for (int c = 0; c < HID; ++c) wv[c] = w2l[(cin * KK + k) * HID + c];
            #pragma unroll
            for (int q = 0; q < 4; ++q)
                #pragma unroll
                for (int c = 0; c < HID; ++c)
                    acc[q][c] = fmaf(hw[q][k], wv[c], acc[q][c]);
        }
    }

    // relu + per-lane partial pool sums
    float lsum[HID];
    #pragma unroll
    for (int c = 0; c < HID; ++c) {
        float v = 0.f;
        #pragma unroll
        for (int q = 0; q < 4; ++q) v += fmaxf(acc[q][c], 0.f);
        lsum[c] = v;
    }

    // wave butterfly reduction (64 lanes)
    #pragma unroll
    for (int c = 0; c < HID; ++c) {
        float v = lsum[c];
        #pragma unroll
        for (int off = 32; off >= 1; off >>= 1) v += __shfl_xor(v, off, 64);
        if (l == 0) pool[c * DD + s] = v * (1.f / SEG);
    }
    __syncthreads();

    // ---- final GEMV: out[b, f*4 + d] ----
    if (tid < DD) {
        const float* pwr = pw + ((size_t)f * DD + tid) * (HID * DD);
        float o = pb[f * DD + tid];
        #pragma unroll
        for (int i = 0; i < HID * DD; ++i) o = fmaf(pwr[i], pool[i], o);
        out[((size_t)b * NF + f) * DD + tid] = o;
    }
}

extern "C" void kernel_launch(void* const* d_in, const int* in_sizes, int n_in,
                              void* d_out, int out_size, void* d_ws, size_t ws_size,
                              hipStream_t stream) {
    const float* x  = (const float*)d_in[0];
    // d_in[1] = lengths (unused by reference)
    const float* w1 = (const float*)d_in[2];
    const float* b1 = (const float*)d_in[3];
    const float* w2 = (const float*)d_in[4];
    const float* b2 = (const float*)d_in[5];
    const float* pw = (const float*)d_in[6];
    const float* pb = (const float*)d_in[7];
    float* out = (float*)d_out;

    dim3 grid(NF, 128);   // (f, b)
    dim3 block(256);
    branch_kernel<<<grid, block, 0, stream>>>(x, w1, b1, w2, b2, pw, pb, out);
}

// Round 2
// 64.008 us; speedup vs baseline: 2.5992x; 2.5992x over previous
//
#include <hip/hip_runtime.h>
#include <hip/hip_bf16.h>

#define TT   1024
#define NF   32
#define HID  16
#define KK   5
#define DD   4
#define NB   128

typedef short short8 __attribute__((ext_vector_type(8)));
typedef float floatx4 __attribute__((ext_vector_type(4)));

__device__ inline ushort f2bf(float f) {
    union { float f; uint u; } v; v.f = f;
    uint r = v.u + 0x7fffu + ((v.u >> 16) & 1u);
    return (ushort)(r >> 16);
}
__device__ inline uint pack_bf2(float a, float b) {
    union { __hip_bfloat162 h; uint u; } c;
    c.h = __float22bfloat162_rn(make_float2(a, b));
    return c.u;
}

// Block = (b, f). 256 threads = 4 waves; wave s owns pool segment s (256 cols).
// Per wave: 4 time-tiles of 64 cols. conv1 fp32 VALU -> bf16 LDS tile,
// conv2 = 3x mfma_f32_16x16x32_bf16 per 16-col subtile (K = 16 cin x 2 taps).
__global__ __launch_bounds__(256, 4) void fused_kernel(
    const float* __restrict__ x,   // (B, T, F)
    const float* __restrict__ w1,  // (F, HID, 1, K)
    const float* __restrict__ b1,  // (F, HID)
    const float* __restrict__ w2,  // (F, HID, HID, K)
    const float* __restrict__ b2,  // (F, HID)
    const float* __restrict__ pw,  // (F, D, HID*D)
    const float* __restrict__ pb,  // (F, D)
    float* __restrict__ out)       // (B, F*D)
{
    // XCD-bijective swizzle: all 32 fields of 16 consecutive b on one XCD.
    const int h = blockIdx.x;
    const int b = (h & 7) * 16 + ((h >> 3) >> 5);
    const int f = (h >> 3) & 31;

    const int tid  = threadIdx.x;
    const int wave = tid >> 6;
    const int lane = tid & 63;

    __shared__ float  xs[1032];            // xs[i] = x[b][i-4][f], zero-padded
    __shared__ float  b2l[HID];
    __shared__ ushort tile[4][72 * 24];    // per-wave h1 tile, row stride 24 ush (48B)
    __shared__ float  pool_lds[HID * DD];

    // ---- stage x row (strided; L2 absorbs via swizzle) ----
    const float* xb = x + (size_t)b * TT * NF + f;
    for (int i = tid; i < 1032; i += 256) {
        float v = 0.f;
        int t = i - 4;
        if (t >= 0 && t < TT) v = xb[(size_t)t * NF];
        xs[i] = v;
    }
    if (tid < HID) b2l[tid] = b2[f * HID + tid];

    // ---- per-lane conv1 weights: lane handles 4 channels (cg = lane&3) ----
    const int rg = lane >> 2;      // row-in-group 0..15
    const int cg = lane & 3;       // channel group
    float w1v[4][KK], b1v[4];
    {
        const float* w1f = w1 + (size_t)f * HID * KK;
        const float* b1f = b1 + (size_t)f * HID;
        #pragma unroll
        for (int cc = 0; cc < 4; ++cc) {
            b1v[cc] = b1f[4 * cg + cc];
            #pragma unroll
            for (int k = 0; k < KK; ++k) w1v[cc][k] = w1f[(4 * cg + cc) * KK + k];
        }
    }

    // ---- A fragments (w2) for 3 tap-pairs: kk = cin + 16*dk ----
    const int cin0 = ((lane >> 4) & 1) * 8;
    const int dk   = (lane >> 4) >> 1;
    const int crow = lane & 15;
    short8 afrag[3];
    {
        const float* w2f = w2 + (size_t)f * HID * HID * KK;
        #pragma unroll
        for (int p = 0; p < 3; ++p) {
            int k = 2 * p + dk;
            #pragma unroll
            for (int j = 0; j < 8; ++j) {
                float wv = (k < KK) ? w2f[crow * (HID * KK) + (cin0 + j) * KK + k] : 0.f;
                afrag[p][j] = (short)f2bf(wv);
            }
        }
    }
    __syncthreads();

    const int seg   = wave;
    const int t0seg = seg * 256;
    ushort* mytile  = tile[wave];

    float bias[4];
    #pragma unroll
    for (int rr = 0; rr < 4; ++rr) bias[rr] = b2l[(lane >> 4) * 4 + rr];

    float psum[4] = {0.f, 0.f, 0.f, 0.f};

    for (int ti = 0; ti < 4; ++ti) {
        const int t0 = t0seg + ti * 64;

        // ---- conv1: fill tile rows r=0..68 (t = t0-2+r), bf16 ----
        #pragma unroll
        for (int it = 0; it < 5; ++it) {
            int r = rg + 16 * it;
            if (r < 69) {
                int t = t0 - 2 + r;
                uint u0 = 0, u1 = 0;
                if (t >= 0 && t < TT) {
                    float hv[4];
                    #pragma unroll
                    for (int cc = 0; cc < 4; ++cc) {
                        float a = b1v[cc];
                        #pragma unroll
                        for (int k = 0; k < KK; ++k) a = fmaf(w1v[cc][k], xs[t + 2 + k], a);
                        hv[cc] = fmaxf(a, 0.f);
                    }
                    u0 = pack_bf2(hv[0], hv[1]);
                    u1 = pack_bf2(hv[2], hv[3]);
                }
                uint2* dst = reinterpret_cast<uint2*>(&mytile[r * 24 + 4 * cg]);
                *dst = make_uint2(u0, u1);
            }
        }
        // same-wave RAW on LDS: compiler inserts lgkmcnt wait (no barrier needed)

        // ---- conv2: 4 subtiles of 16 cols, 3 mfma each ----
        #pragma unroll
        for (int st = 0; st < 4; ++st) {
            floatx4 acc = {0.f, 0.f, 0.f, 0.f};
            #pragma unroll
            for (int p = 0; p < 3; ++p) {
                int r = st * 16 + crow + 2 * p + dk;   // local row in [0,68]
                const short8 bfrag = *reinterpret_cast<const short8*>(&mytile[r * 24 + cin0]);
                acc = __builtin_amdgcn_mfma_f32_16x16x32_bf16(afrag[p], bfrag, acc, 0, 0, 0);
            }
            #pragma unroll
            for (int rr = 0; rr < 4; ++rr)
                psum[rr] += fmaxf(acc[rr] + bias[rr], 0.f);
        }
    }

    // ---- pool: reduce psum across the 16-lane column groups ----
    #pragma unroll
    for (int rr = 0; rr < 4; ++rr) {
        float v = psum[rr];
        v += __shfl_xor(v, 1, 64);
        v += __shfl_xor(v, 2, 64);
        v += __shfl_xor(v, 4, 64);
        v += __shfl_xor(v, 8, 64);
        if (crow == 0)
            pool_lds[((lane >> 4) * 4 + rr) * DD + seg] = v * (1.f / 256.f);
    }
    __syncthreads();

    // ---- final GEMV: out[b, f*4 + d] ----
    if (tid < DD) {
        const float* pwr = pw + ((size_t)f * DD + tid) * (HID * DD);
        float o = pb[f * DD + tid];
        #pragma unroll
        for (int i = 0; i < HID * DD; ++i) o = fmaf(pwr[i], pool_lds[i], o);
        out[((size_t)b * NF + f) * DD + tid] = o;
    }
}

extern "C" void kernel_launch(void* const* d_in, const int* in_sizes, int n_in,
                              void* d_out, int out_size, void* d_ws, size_t ws_size,
                              hipStream_t stream) {
    const float* x  = (const float*)d_in[0];
    // d_in[1] = lengths (unused by reference)
    const float* w1 = (const float*)d_in[2];
    const float* b1 = (const float*)d_in[3];
    const float* w2 = (const float*)d_in[4];
    const float* b2 = (const float*)d_in[5];
    const float* pw = (const float*)d_in[6];
    const float* pb = (const float*)d_in[7];
    float* out = (float*)d_out;

    fused_kernel<<<dim3(NB * NF), dim3(256), 0, stream>>>(x, w1, b1, w2, b2, pw, pb, out);
}